// Round 15
// baseline (808.749 us; speedup 1.0000x reference)
//
#include <hip/hip_runtime.h>
#include <stdint.h>

typedef unsigned short u16;
typedef unsigned int   u32;
typedef _Float16 f16x8 __attribute__((ext_vector_type(8)));
typedef __attribute__((ext_vector_type(16))) float f16v;

#define JJ 17
#define CC 128
#define BB 7
#define ROWS (BB*JJ)     // 119
#define PP 128
#define XP 136           // u16 pitch: 272B rows -> 16B-aligned frags, measured conflict-free
#define H1P 130          // f32 pitch for h1 (aliases X planes)
#define NLAYERS 5
#define NT 1024

#define XBUF_BYTES (2*PP*XP*2)            // 69632: xh + xl u16 planes; h1 f32[128][130] alias
#define W_OFF      XBUF_BYTES             // 69632: Wlds [2][128][XP] u16 = 69632
#define ADJS_OFF   (W_OFF + 2*PP*XP*2)    // 139264
#define DIAG_OFF   (ADJS_OFF + 1216)      // 140480
#define BIAS_OFF   (DIAG_OFF + 512)       // 140992
#define LDS_BYTES  (BIAS_OFF + 512)       // 141504 -> 1 block/CU, 16 waves (4/SIMD)

#define MFMA __builtin_amdgcn_mfma_f32_32x32x16_f16

__device__ __forceinline__ u16 h2b(_Float16 h) {
  union { _Float16 h; u16 b; } c; c.h = h; return c.b;
}
__device__ __forceinline__ _Float16 b2h(u16 b) {
  union { u16 b; _Float16 h; } c; c.b = b; return c.h;
}
__device__ __forceinline__ float wred(float v) {
  #pragma unroll
  for (int m = 32; m >= 1; m >>= 1) v += __shfl_xor(v, m, 64);
  return v;
}

// ---- setup: W0/W1 -> f16, frag layout ws[w][col][k] ----
__global__ void __launch_bounds__(256)
wprep(const float* __restrict__ W0, const float* __restrict__ W1,
      u16* __restrict__ wsH)
{
  __shared__ float wt[64*130];
  const int w01 = blockIdx.x;
  const float* Wp = w01 ? W1 : W0;
  const int tid = threadIdx.x;
  for (int kh = 0; kh < 2; ++kh) {
    if (kh) __syncthreads();
    #pragma unroll
    for (int i = 0; i < 32; ++i) {
      int idx = tid + i*256;           // [64 kk][128 col] coalesced read
      int kk = idx >> 7, col = idx & 127;
      wt[kk*130 + col] = Wp[(kh*64 + kk)*128 + col];
    }
    __syncthreads();
    #pragma unroll
    for (int i = 0; i < 32; ++i) {
      int idx = tid + i*256;           // [128 col][64 kk] coalesced write
      int col = idx >> 6, kk = idx & 63;
      wsH[(size_t)(w01*128 + col)*128 + kh*64 + kk] = h2b((_Float16)wt[kk*130 + col]);
    }
  }
}

__global__ void __launch_bounds__(NT, 4)
gconv_fused(const float* __restrict__ x, const float* __restrict__ x0,
            const float* __restrict__ adj, const u16* __restrict__ wsH,
            const float* __restrict__ bvec, const float* __restrict__ gamma,
            const float* __restrict__ beta, float* __restrict__ out, int totRows)
{
  extern __shared__ char smem[];
  u16*   xh    = (u16*)smem;                   // [PP][XP] x hi (f16)
  u16*   xl    = xh + PP*XP;                   // x lo (f16)
  float* h1    = (float*)smem;                 // alias, [PP][H1P] f32
  u16*   wlds  = (u16*)(smem + W_OFF);         // [2][128][XP] f16 W, frag layout
  float* adjs  = (float*)(smem + ADJS_OFF);    // [289] 0.8*adj, diag zeroed
  float* diag8 = (float*)(smem + DIAG_OFF);    // [128]
  float* biasl = (float*)(smem + BIAS_OFF);    // [128]

  const int tid  = threadIdx.x;
  const int lane = tid & 63;
  const int wid  = tid >> 6;        // 0..15
  const int wm   = wid >> 2;        // 0..3  M-tile (32 rows)
  const int wn   = wid & 3;         // 0..3  N-tile (32 cols)
  const int g    = lane >> 5;
  const int nl   = lane & 31;
  const int ccol = wn*32 + nl;
  const int grow0 = blockIdx.x * ROWS;

  // ---- W (f16) -> LDS: pure 16B copies from precomputed ws (L2-hot)
  {
    int el = tid * 32;                 // 0..32767, 32 contiguous u16/thread
    int w01 = el >> 14, rem = el & 16383;
    int col = rem >> 7, k0 = rem & 127;
    const u16* src = wsH + el;
    u16* dst = &wlds[(w01*128 + col)*XP + k0];
    #pragma unroll
    for (int c = 0; c < 4; ++c)
      *(uint4*)(dst + c*8) = *(const uint4*)(src + c*8);
  }

  // ---- x -> xh/xl f16 planes (float4 in); pad rows zero
  #pragma unroll
  for (int i = 0; i < 4; ++i) {
    int el4 = tid + i*NT;              // 4096 float4 = 128 rows x 128
    int r = el4 >> 5, c4 = (el4 & 31) << 2;
    float4 v = make_float4(0.f, 0.f, 0.f, 0.f);
    if (r < ROWS && (grow0 + r) < totRows)
      v = *(const float4*)&x[(size_t)(grow0 + r)*CC + c4];
    u16 sh[4], sl[4];
    float vv[4] = {v.x, v.y, v.z, v.w};
    #pragma unroll
    for (int e = 0; e < 4; ++e) {
      _Float16 hh = (_Float16)vv[e];
      sh[e] = h2b(hh);
      sl[e] = h2b((_Float16)(vv[e] - (float)hh));
    }
    *(uint2*)&xh[r*XP + c4] = make_uint2((u32)sh[0] | ((u32)sh[1]<<16), (u32)sh[2] | ((u32)sh[3]<<16));
    *(uint2*)&xl[r*XP + c4] = make_uint2((u32)sl[0] | ((u32)sl[1]<<16), (u32)sl[2] | ((u32)sl[3]<<16));
  }
  if (tid < JJ*JJ) {
    int j = tid / JJ, k = tid - j*JJ;
    adjs[tid] = (j == k) ? 0.f : 0.8f * adj[tid];
  }
  if (tid >= 512 && tid < 512 + PP) {
    int t = tid - 512;
    int j = t % JJ;
    diag8[t] = (t < ROWS) ? 0.8f * adj[j*JJ + j] : 0.f;
  }
  if (tid >= 768 && tid < 768 + CC) biasl[tid - 768] = bvec[tid - 768];
  __syncthreads();

  const int arow = (wm*32 + nl)*XP + 8*g;      // A-frag base (per ks add 16)
  const int brow0 = ccol*XP + 8*g;             // W0 frag base
  const int brow1 = brow0 + 128*XP;            // W1

  // ================= layer loop =================
  #pragma unroll 1
  for (int layer = 0; layer < NLAYERS; ++layer) {
    f16v acc0, acc1;
    #pragma unroll
    for (int i = 0; i < 16; ++i) { acc0[i] = 0.f; acc1[i] = 0.f; }

    // ---- GEMM: per ks: 4x ds_read_b128 + 4 MFMA; 4 waves/SIMD hide latency
    #pragma unroll
    for (int ks = 0; ks < 8; ++ks) {
      const int o = ks*16;
      f16x8 ah = *(const f16x8*)&xh[arow + o];
      f16x8 al = *(const f16x8*)&xl[arow + o];
      f16x8 b0 = *(const f16x8*)&wlds[brow0 + o];
      f16x8 b1 = *(const f16x8*)&wlds[brow1 + o];
      acc0 = MFMA(ah, b0, acc0, 0, 0, 0);
      acc0 = MFMA(al, b0, acc0, 0, 0, 0);
      acc1 = MFMA(ah, b1, acc1, 0, 0, 0);
      acc1 = MFMA(al, b1, acc1, 0, 0, 0);
      __builtin_amdgcn_sched_barrier(0);   // cap fragment liveness per K-step
    }
    __syncthreads();   // (1) xh/xl reads done (h1 aliases them)

    // ---- epilogue: acc1 (X@W1) -> h1
    #pragma unroll
    for (int q = 0; q < 16; ++q) {
      int row = wm*32 + (q&3) + 8*(q>>2) + 4*g;
      h1[row*H1P + ccol] = acc1[q];
    }
    __syncthreads();   // (2) h1 complete

    // ---- joint mix in place: 14 waves (elem e = wid>>1, col-half = wid&1)
    if (wid < 14) {
      const int e = wid >> 1, half = wid & 1;
      const int base = e*JJ*H1P + half*64 + lane;
      float xv[JJ];
      #pragma unroll
      for (int k = 0; k < JJ; ++k) xv[k] = h1[base + k*H1P];
      #pragma unroll 4
      for (int j = 0; j < JJ; ++j) {
        float s = 0.f;
        #pragma unroll
        for (int k = 0; k < JJ; ++k) s += adjs[j*JJ + k] * xv[k];
        h1[base + j*H1P] = s;
      }
    }
    __syncthreads();   // (3) mix complete

    // ---- combine A: gather into regs (x0 lazy f32, L2-hot after layer 0)
    float tmp[16];
    #pragma unroll
    for (int q = 0; q < 16; ++q) {
      int row = wm*32 + (q&3) + 8*(q>>2) + 4*g;
      int grow = grow0 + row;
      float x0v = (row < ROWS && grow < totRows) ? x0[(size_t)grow*CC + ccol] : 0.f;
      tmp[q] = 0.2f*x0v + diag8[row]*acc0[q] + h1[row*H1P + ccol] + biasl[ccol];
    }
    __syncthreads();   // (4) all h1 reads drained before alias overwrite

    // ---- combine B: regs -> X planes (or keep f32 in h1 on final layer)
    if (layer < NLAYERS - 1) {
      #pragma unroll
      for (int q = 0; q < 16; ++q) {
        int row = wm*32 + (q&3) + 8*(q>>2) + 4*g;
        _Float16 hh = (_Float16)tmp[q];
        xh[row*XP + ccol] = h2b(hh);
        xl[row*XP + ccol] = h2b((_Float16)(tmp[q] - (float)hh));
      }
    } else {
      #pragma unroll
      for (int q = 0; q < 16; ++q) {
        int row = wm*32 + (q&3) + 8*(q>>2) + 4*g;
        h1[row*H1P + ccol] = tmp[q];
      }
    }
    __syncthreads();   // (5) ready for next layer / LN
  }

  // ---- LayerNorm + store (reads f32 h1), 16 waves
  float ga = gamma[lane], g2 = gamma[64+lane];
  float ba = beta[lane],  b2f = beta[64+lane];
  #pragma unroll 1
  for (int i = 0; i < 8; ++i) {
    int r = wid + 16*i;            // wave-uniform, 0..127
    if (r >= ROWS) continue;
    int grow = grow0 + r;
    if (grow >= totRows) continue;
    float xa = h1[r*H1P + lane];
    float xc = h1[r*H1P + 64 + lane];
    float mu = wred(xa + xc) * (1.f/128.f);
    float da = xa - mu, dc = xc - mu;
    float vs = wred(da*da + dc*dc) * (1.f/128.f);
    float rs = rsqrtf(vs + 1e-10f);
    size_t ob = (size_t)grow*CC;
    out[ob + lane]      = da*rs*ga + ba;
    out[ob + 64 + lane] = dc*rs*g2 + b2f;
  }
}

extern "C" void kernel_launch(void* const* d_in, const int* in_sizes, int n_in,
                              void* d_out, int out_size, void* d_ws, size_t ws_size,
                              hipStream_t stream) {
  const float* x   = (const float*)d_in[0];
  const float* x0  = (const float*)d_in[1];
  const float* adj = (const float*)d_in[2];
  const float* W0  = (const float*)d_in[3];
  const float* W1  = (const float*)d_in[4];
  const float* bv  = (const float*)d_in[5];
  const float* ga  = (const float*)d_in[6];
  const float* be  = (const float*)d_in[7];
  u16* wsH = (u16*)d_ws;                    // [2][128][128] f16
  int totRows = in_sizes[0] / CC;
  int nBatch  = totRows / JJ;
  int grid    = (nBatch + BB - 1) / BB;
  wprep<<<dim3(2), dim3(256), 0, stream>>>(W0, W1, wsH);
  hipFuncSetAttribute((const void*)gconv_fused,
                      hipFuncAttributeMaxDynamicSharedMemorySize, LDS_BYTES);
  gconv_fused<<<dim3(grid), dim3(NT), LDS_BYTES, stream>>>(
      x, x0, adj, wsH, bv, ga, be, (float*)d_out, totRows);
}

// Round 16
// 566.710 us; speedup vs baseline: 1.4271x; 1.4271x over previous
//
#include <hip/hip_runtime.h>
#include <stdint.h>

typedef unsigned short u16;
typedef unsigned int   u32;
typedef _Float16 f16x4 __attribute__((ext_vector_type(4)));
typedef _Float16 f16x8 __attribute__((ext_vector_type(8)));
typedef __attribute__((ext_vector_type(16))) float f16v;

#define JJ 17
#define CC 128
#define BB 7
#define ROWS (BB*JJ)     // 119
#define PP 128
#define XP 132           // u16 pitch: 264B rows -> b64 frags, 2-bank stride (free)
#define H1P 130          // f32 pitch for h1
#define NLAYERS 5
#define NT 1024

#define H1_BYTES   (PP*H1P*4)             // 66560 (xh u16[128][132]=33792 aliases its start)
#define W_OFF      H1_BYTES               // 66560
#define W_BYTES    (2*PP*XP*2)            // 67584
#define ADJS_OFF   (W_OFF + W_BYTES)      // 134144
#define DIAG_OFF   (ADJS_OFF + 1216)      // 135360
#define BIAS_OFF   (DIAG_OFF + 512)       // 135872
#define LDS_BYTES  (BIAS_OFF + 512)       // 136384 -> 1 block/CU, 16 waves (4/SIMD)

#define MFMA __builtin_amdgcn_mfma_f32_32x32x16_f16

__device__ __forceinline__ u16 h2b(_Float16 h) {
  union { _Float16 h; u16 b; } c; c.h = h; return c.b;
}
__device__ __forceinline__ _Float16 b2h(u16 b) {
  union { u16 b; _Float16 h; } c; c.b = b; return c.h;
}
__device__ __forceinline__ f16x8 cmbh(f16x4 a, f16x4 b) {
  f16x8 r;
  r[0]=a[0]; r[1]=a[1]; r[2]=a[2]; r[3]=a[3];
  r[4]=b[0]; r[5]=b[1]; r[6]=b[2]; r[7]=b[3];
  return r;
}
__device__ __forceinline__ float wred(float v) {
  #pragma unroll
  for (int m = 32; m >= 1; m >>= 1) v += __shfl_xor(v, m, 64);
  return v;
}

// ---- setup: W0/W1 -> f16, frag layout ws[w][col][k] ----
__global__ void __launch_bounds__(256)
wprep(const float* __restrict__ W0, const float* __restrict__ W1,
      u16* __restrict__ wsH)
{
  __shared__ float wt[64*130];
  const int w01 = blockIdx.x;
  const float* Wp = w01 ? W1 : W0;
  const int tid = threadIdx.x;
  for (int kh = 0; kh < 2; ++kh) {
    if (kh) __syncthreads();
    #pragma unroll
    for (int i = 0; i < 32; ++i) {
      int idx = tid + i*256;           // [64 kk][128 col] coalesced read
      int kk = idx >> 7, col = idx & 127;
      wt[kk*130 + col] = Wp[(kh*64 + kk)*128 + col];
    }
    __syncthreads();
    #pragma unroll
    for (int i = 0; i < 32; ++i) {
      int idx = tid + i*256;           // [128 col][64 kk] coalesced write
      int col = idx >> 6, kk = idx & 63;
      wsH[(size_t)(w01*128 + col)*128 + kh*64 + kk] = h2b((_Float16)wt[kk*130 + col]);
    }
  }
}

__global__ void __launch_bounds__(NT, 4)
gconv_fused(const float* __restrict__ x, const float* __restrict__ x0,
            const float* __restrict__ adj, const u16* __restrict__ wsH,
            const float* __restrict__ bvec, const float* __restrict__ gamma,
            const float* __restrict__ beta, float* __restrict__ out, int totRows)
{
  extern __shared__ char smem[];
  u16*   xh    = (u16*)smem;                   // [PP][XP] x (f16), aliases h1 start
  float* h1    = (float*)smem;                 // [PP][H1P] f32
  u16*   wlds  = (u16*)(smem + W_OFF);         // [2][128][XP] f16 W, frag layout
  float* adjs  = (float*)(smem + ADJS_OFF);    // [289] 0.8*adj, diag zeroed
  float* diag8 = (float*)(smem + DIAG_OFF);    // [128]
  float* biasl = (float*)(smem + BIAS_OFF);    // [128]

  const int tid  = threadIdx.x;
  const int lane = tid & 63;
  const int wid  = tid >> 6;        // 0..15
  const int wm   = wid >> 2;        // 0..3  M-tile (32 rows)
  const int wn   = wid & 3;         // 0..3  N-tile (32 cols)
  const int g    = lane >> 5;
  const int nl   = lane & 31;
  const int ccol = wn*32 + nl;
  const int grow0 = blockIdx.x * ROWS;

  // ---- W (f16) -> LDS: 32 contiguous u16/thread, 8B writes (264B col pitch)
  {
    int el = tid * 32;                 // 0..32767
    int w01 = el >> 14, rem = el & 16383;
    int col = rem >> 7, k0 = rem & 127;
    const u16* src = wsH + el;
    u16* dst = &wlds[(w01*128 + col)*XP + k0];
    #pragma unroll
    for (int c = 0; c < 8; ++c)
      *(uint2*)(dst + c*4) = *(const uint2*)(src + c*4);
  }

  // ---- x0 -> 16 packed-f16 regs (accumulator layout), read once
  u32 x0p[8];
  #pragma unroll
  for (int qp = 0; qp < 8; ++qp) {
    u32 pk = 0;
    #pragma unroll
    for (int h = 0; h < 2; ++h) {
      int q = qp*2 + h;
      int row = wm*32 + (q&3) + 8*(q>>2) + 4*g;
      int grow = grow0 + row;
      u16 bits = 0;
      if (row < ROWS && grow < totRows)
        bits = h2b((_Float16)x0[(size_t)grow*CC + ccol]);
      pk |= ((u32)bits) << (16*h);
    }
    x0p[qp] = pk;
  }

  // ---- x -> xh f16 plane (float4 in); pad rows zero
  #pragma unroll
  for (int i = 0; i < 4; ++i) {
    int el4 = tid + i*NT;              // 4096 float4 = 128 rows x 128
    int r = el4 >> 5, c4 = (el4 & 31) << 2;
    float4 v = make_float4(0.f, 0.f, 0.f, 0.f);
    if (r < ROWS && (grow0 + r) < totRows)
      v = *(const float4*)&x[(size_t)(grow0 + r)*CC + c4];
    u16 s0 = h2b((_Float16)v.x), s1 = h2b((_Float16)v.y);
    u16 s2 = h2b((_Float16)v.z), s3 = h2b((_Float16)v.w);
    *(uint2*)&xh[r*XP + c4] = make_uint2((u32)s0 | ((u32)s1<<16), (u32)s2 | ((u32)s3<<16));
  }
  if (tid < JJ*JJ) {
    int j = tid / JJ, k = tid - j*JJ;
    adjs[tid] = (j == k) ? 0.f : 0.8f * adj[tid];
  }
  if (tid >= 512 && tid < 512 + PP) {
    int t = tid - 512;
    int j = t % JJ;
    diag8[t] = (t < ROWS) ? 0.8f * adj[j*JJ + j] : 0.f;
  }
  if (tid >= 768 && tid < 768 + CC) biasl[tid - 768] = bvec[tid - 768];
  __syncthreads();

  const int arow = (wm*32 + nl)*XP;            // A base (+= ks*16 + 8g)
  const int bb0  = ccol*XP;                    // W0 frag base
  const int bb1  = bb0 + 128*XP;               // W1

  // ================= layer loop (no global traffic) =================
  #pragma unroll 1
  for (int layer = 0; layer < NLAYERS; ++layer) {
    f16v acc0, acc1;
    #pragma unroll
    for (int i = 0; i < 16; ++i) { acc0[i] = 0.f; acc1[i] = 0.f; }

    // ---- GEMM: per ks: 3 b64-pair reads + 2 MFMA
    #pragma unroll
    for (int ks = 0; ks < 8; ++ks) {
      const int o = ks*16 + 8*g;
      f16x8 ah = cmbh(*(const f16x4*)&xh[arow + o],   *(const f16x4*)&xh[arow + o + 4]);
      f16x8 b0 = cmbh(*(const f16x4*)&wlds[bb0 + o],  *(const f16x4*)&wlds[bb0 + o + 4]);
      f16x8 b1 = cmbh(*(const f16x4*)&wlds[bb1 + o],  *(const f16x4*)&wlds[bb1 + o + 4]);
      acc0 = MFMA(ah, b0, acc0, 0, 0, 0);
      acc1 = MFMA(ah, b1, acc1, 0, 0, 0);
      __builtin_amdgcn_sched_barrier(0);   // cap fragment liveness per K-step
    }
    __syncthreads();   // (1) X reads done (h1 aliases xh)

    // ---- epilogue: acc1 (X@W1) -> h1 (clobbers X region; X is dead)
    #pragma unroll
    for (int q = 0; q < 16; ++q) {
      int row = wm*32 + (q&3) + 8*(q>>2) + 4*g;
      h1[row*H1P + ccol] = acc1[q];
    }
    __syncthreads();   // (2) h1 complete

    // ---- joint mix in place: 14 waves (elem = wid>>1, col-half = wid&1)
    if (wid < 14) {
      const int e = wid >> 1, half = wid & 1;
      const int base = e*JJ*H1P + half*64 + lane;
      float xv[JJ];
      #pragma unroll
      for (int k = 0; k < JJ; ++k) xv[k] = h1[base + k*H1P];
      #pragma unroll 4
      for (int j = 0; j < JJ; ++j) {
        float s = 0.f;
        #pragma unroll
        for (int k = 0; k < JJ; ++k) s += adjs[j*JJ + k] * xv[k];
        h1[base + j*H1P] = s;
      }
    }
    __syncthreads();   // (3) mix complete

    if (layer < NLAYERS - 1) {
      // ---- combine A: fold into acc0 (reg-resident; no spill)
      #pragma unroll
      for (int q = 0; q < 16; ++q) {
        int row = wm*32 + (q&3) + 8*(q>>2) + 4*g;
        float x0v = (float)b2h((u16)(x0p[q>>1] >> (16*(q&1))));
        acc0[q] = 0.2f*x0v + diag8[row]*acc0[q] + h1[row*H1P + ccol] + biasl[ccol];
      }
      __syncthreads();   // (4) all h1 reads drained before alias overwrite

      // ---- combine B: acc0 -> X plane (f16 single)
      #pragma unroll
      for (int q = 0; q < 16; ++q) {
        int row = wm*32 + (q&3) + 8*(q>>2) + 4*g;
        xh[row*XP + ccol] = h2b((_Float16)acc0[q]);
      }
      __syncthreads();   // (5) X ready for next layer
    } else {
      // final layer: own-slot RMW into h1, keep f32 for LN
      #pragma unroll
      for (int q = 0; q < 16; ++q) {
        int row = wm*32 + (q&3) + 8*(q>>2) + 4*g;
        float x0v = (float)b2h((u16)(x0p[q>>1] >> (16*(q&1))));
        h1[row*H1P + ccol] = 0.2f*x0v + diag8[row]*acc0[q] + h1[row*H1P + ccol] + biasl[ccol];
      }
      __syncthreads();   // (4) ready for LN
    }
  }

  // ---- LayerNorm + store (reads f32 h1), 16 waves
  float ga = gamma[lane], g2 = gamma[64+lane];
  float ba = beta[lane],  b2f = beta[64+lane];
  #pragma unroll 1
  for (int i = 0; i < 8; ++i) {
    int r = wid + 16*i;            // wave-uniform, 0..127
    if (r >= ROWS) continue;
    int grow = grow0 + r;
    if (grow >= totRows) continue;
    float xa = h1[r*H1P + lane];
    float xc = h1[r*H1P + 64 + lane];
    float mu = wred(xa + xc) * (1.f/128.f);
    float da = xa - mu, dc = xc - mu;
    float vs = wred(da*da + dc*dc) * (1.f/128.f);
    float rs = rsqrtf(vs + 1e-10f);
    size_t ob = (size_t)grow*CC;
    out[ob + lane]      = da*rs*ga + ba;
    out[ob + 64 + lane] = dc*rs*g2 + b2f;
  }
}

extern "C" void kernel_launch(void* const* d_in, const int* in_sizes, int n_in,
                              void* d_out, int out_size, void* d_ws, size_t ws_size,
                              hipStream_t stream) {
  const float* x   = (const float*)d_in[0];
  const float* x0  = (const float*)d_in[1];
  const float* adj = (const float*)d_in[2];
  const float* W0  = (const float*)d_in[3];
  const float* W1  = (const float*)d_in[4];
  const float* bv  = (const float*)d_in[5];
  const float* ga  = (const float*)d_in[6];
  const float* be  = (const float*)d_in[7];
  u16* wsH = (u16*)d_ws;                    // [2][128][128] f16
  int totRows = in_sizes[0] / CC;
  int nBatch  = totRows / JJ;
  int grid    = (nBatch + BB - 1) / BB;
  wprep<<<dim3(2), dim3(256), 0, stream>>>(W0, W1, wsH);
  hipFuncSetAttribute((const void*)gconv_fused,
                      hipFuncAttributeMaxDynamicSharedMemorySize, LDS_BYTES);
  gconv_fused<<<dim3(grid), dim3(NT), LDS_BYTES, stream>>>(
      x, x0, adj, wsH, bv, ga, be, (float*)d_out, totRows);
}

// Round 17
// 493.460 us; speedup vs baseline: 1.6389x; 1.1484x over previous
//
#include <hip/hip_runtime.h>
#include <stdint.h>

typedef unsigned short u16;
typedef unsigned int   u32;
typedef _Float16 f16x4 __attribute__((ext_vector_type(4)));
typedef _Float16 f16x8 __attribute__((ext_vector_type(8)));
typedef __attribute__((ext_vector_type(16))) float f16v;

#define JJ 17
#define CC 128
#define BB 7
#define ROWS (BB*JJ)     // 119
#define PP 128
#define XP 132           // u16 pitch: 264B rows -> b64 frags, 2-bank stride (free)
#define H1P 130          // f32 pitch for h1
#define NLAYERS 5
#define NT 1024
#define AP 20            // adjc row pitch (floats): 5 aligned float4 per row

#define H1_BYTES   (PP*H1P*4)             // 66560 (xh u16[128][132]=33792 aliases its start)
#define W_OFF      H1_BYTES               // 66560
#define W_BYTES    (2*PP*XP*2)            // 67584
#define DIAG_OFF   (W_OFF + W_BYTES)      // 134144
#define BIAS_OFF   (DIAG_OFF + 512)       // 134656
#define LDS_BYTES  (BIAS_OFF + 512)       // 135168 -> 1 block/CU, 16 waves (4/SIMD)

#define MFMA __builtin_amdgcn_mfma_f32_32x32x16_f16

__device__ __forceinline__ u16 h2b(_Float16 h) {
  union { _Float16 h; u16 b; } c; c.h = h; return c.b;
}
__device__ __forceinline__ _Float16 b2h(u16 b) {
  union { u16 b; _Float16 h; } c; c.b = b; return c.h;
}
__device__ __forceinline__ f16x8 cmbh(f16x4 a, f16x4 b) {
  f16x8 r;
  r[0]=a[0]; r[1]=a[1]; r[2]=a[2]; r[3]=a[3];
  r[4]=b[0]; r[5]=b[1]; r[6]=b[2]; r[7]=b[3];
  return r;
}
__device__ __forceinline__ float wred(float v) {
  #pragma unroll
  for (int m = 32; m >= 1; m >>= 1) v += __shfl_xor(v, m, 64);
  return v;
}

// ---- setup: W0/W1 -> f16 frag layout; adjc = 0.8*adj, diag zeroed, [17][20] padded
__global__ void __launch_bounds__(256)
wprep(const float* __restrict__ W0, const float* __restrict__ W1,
      const float* __restrict__ adj, u16* __restrict__ wsH,
      float* __restrict__ adjc)
{
  __shared__ float wt[64*130];
  const int w01 = blockIdx.x;
  const float* Wp = w01 ? W1 : W0;
  const int tid = threadIdx.x;
  if (w01 == 0) {
    for (int t = tid; t < JJ*AP; t += 256) {
      int j = t / AP, k = t - j*AP;
      adjc[t] = (k < JJ && k != j) ? 0.8f * adj[j*JJ + k] : 0.f;
    }
  }
  for (int kh = 0; kh < 2; ++kh) {
    if (kh) __syncthreads();
    #pragma unroll
    for (int i = 0; i < 32; ++i) {
      int idx = tid + i*256;           // [64 kk][128 col] coalesced read
      int kk = idx >> 7, col = idx & 127;
      wt[kk*130 + col] = Wp[(kh*64 + kk)*128 + col];
    }
    __syncthreads();
    #pragma unroll
    for (int i = 0; i < 32; ++i) {
      int idx = tid + i*256;           // [128 col][64 kk] coalesced write
      int col = idx >> 6, kk = idx & 63;
      wsH[(size_t)(w01*128 + col)*128 + kh*64 + kk] = h2b((_Float16)wt[kk*130 + col]);
    }
  }
}

__global__ void __launch_bounds__(NT, 4)
gconv_fused(const float* __restrict__ x, const float* __restrict__ x0,
            const float* __restrict__ adj, const u16* __restrict__ wsH,
            const float* __restrict__ adjc, const float* __restrict__ bvec,
            const float* __restrict__ gamma, const float* __restrict__ beta,
            float* __restrict__ out, int totRows)
{
  extern __shared__ char smem[];
  u16*   xh    = (u16*)smem;                   // [PP][XP] x (f16), aliases h1 start
  float* h1    = (float*)smem;                 // [PP][H1P] f32
  u16*   wlds  = (u16*)(smem + W_OFF);         // [2][128][XP] f16 W, frag layout
  float* diag8 = (float*)(smem + DIAG_OFF);    // [128]
  float* biasl = (float*)(smem + BIAS_OFF);    // [128]

  const int tid  = threadIdx.x;
  const int lane = tid & 63;
  const int wid  = tid >> 6;        // 0..15
  const int wm   = wid >> 2;        // 0..3  M-tile (32 rows)
  const int wn   = wid & 3;         // 0..3  N-tile (32 cols)
  const int g    = lane >> 5;
  const int nl   = lane & 31;
  const int ccol = wn*32 + nl;
  const int grow0 = blockIdx.x * ROWS;

  // ---- W (f16) -> LDS: 32 contiguous u16/thread, 8B writes (264B col pitch)
  {
    int el = tid * 32;                 // 0..32767
    int w01 = el >> 14, rem = el & 16383;
    int col = rem >> 7, k0 = rem & 127;
    const u16* src = wsH + el;
    u16* dst = &wlds[(w01*128 + col)*XP + k0];
    #pragma unroll
    for (int c = 0; c < 8; ++c)
      *(uint2*)(dst + c*4) = *(const uint2*)(src + c*4);
  }

  // ---- x0 -> 16 packed-f16 regs (accumulator layout), read once
  u32 x0p[8];
  #pragma unroll
  for (int qp = 0; qp < 8; ++qp) {
    u32 pk = 0;
    #pragma unroll
    for (int h = 0; h < 2; ++h) {
      int q = qp*2 + h;
      int row = wm*32 + (q&3) + 8*(q>>2) + 4*g;
      int grow = grow0 + row;
      u16 bits = 0;
      if (row < ROWS && grow < totRows)
        bits = h2b((_Float16)x0[(size_t)grow*CC + ccol]);
      pk |= ((u32)bits) << (16*h);
    }
    x0p[qp] = pk;
  }

  // ---- x -> xh f16 plane (float4 in); pad rows zero
  #pragma unroll
  for (int i = 0; i < 4; ++i) {
    int el4 = tid + i*NT;              // 4096 float4 = 128 rows x 128
    int r = el4 >> 5, c4 = (el4 & 31) << 2;
    float4 v = make_float4(0.f, 0.f, 0.f, 0.f);
    if (r < ROWS && (grow0 + r) < totRows)
      v = *(const float4*)&x[(size_t)(grow0 + r)*CC + c4];
    u16 s0 = h2b((_Float16)v.x), s1 = h2b((_Float16)v.y);
    u16 s2 = h2b((_Float16)v.z), s3 = h2b((_Float16)v.w);
    *(uint2*)&xh[r*XP + c4] = make_uint2((u32)s0 | ((u32)s1<<16), (u32)s2 | ((u32)s3<<16));
  }
  if (tid >= 512 && tid < 512 + PP) {
    int t = tid - 512;
    int j = t % JJ;
    diag8[t] = (t < ROWS) ? 0.8f * adj[j*JJ + j] : 0.f;
  }
  if (tid >= 768 && tid < 768 + CC) biasl[tid - 768] = bvec[tid - 768];
  __syncthreads();

  const int arow = (wm*32 + nl)*XP;            // A base (+= ks*16 + 8g)
  const int bb0  = ccol*XP;                    // W0 frag base
  const int bb1  = bb0 + 128*XP;               // W1
  const float4* adj4 = (const float4*)adjc;    // [17][5] float4 rows, L1-hot

  // ================= layer loop =================
  #pragma unroll 1
  for (int layer = 0; layer < NLAYERS; ++layer) {
    f16v acc0, acc1;
    #pragma unroll
    for (int i = 0; i < 16; ++i) { acc0[i] = 0.f; acc1[i] = 0.f; }

    // ---- GEMM: per ks: 3 b64-pair reads + 2 MFMA
    #pragma unroll
    for (int ks = 0; ks < 8; ++ks) {
      const int o = ks*16 + 8*g;
      f16x8 ah = cmbh(*(const f16x4*)&xh[arow + o],   *(const f16x4*)&xh[arow + o + 4]);
      f16x8 b0 = cmbh(*(const f16x4*)&wlds[bb0 + o],  *(const f16x4*)&wlds[bb0 + o + 4]);
      f16x8 b1 = cmbh(*(const f16x4*)&wlds[bb1 + o],  *(const f16x4*)&wlds[bb1 + o + 4]);
      acc0 = MFMA(ah, b0, acc0, 0, 0, 0);
      acc1 = MFMA(ah, b1, acc1, 0, 0, 0);
      __builtin_amdgcn_sched_barrier(0);   // cap fragment liveness per K-step
    }
    __syncthreads();   // (1) X reads done (h1 aliases xh)

    // ---- epilogue: acc1 (X@W1) -> h1 (clobbers X region; X is dead)
    #pragma unroll
    for (int q = 0; q < 16; ++q) {
      int row = wm*32 + (q&3) + 8*(q>>2) + 4*g;
      h1[row*H1P + ccol] = acc1[q];
    }
    __syncthreads();   // (2) h1 complete

    // ---- joint mix in place: 14 waves; adjc from VMEM (off the LDS pipe)
    if (wid < 14) {
      const int e = wid >> 1, half = wid & 1;
      const int base = e*JJ*H1P + half*64 + lane;
      float xv[JJ];
      #pragma unroll
      for (int k = 0; k < JJ; ++k) xv[k] = h1[base + k*H1P];
      #pragma unroll 4
      for (int j = 0; j < JJ; ++j) {
        float4 a0 = adj4[j*5+0], a1 = adj4[j*5+1];
        float4 a2 = adj4[j*5+2], a3 = adj4[j*5+3];
        float4 a4 = adj4[j*5+4];                 // only .x (k=16) nonzero
        float s = a0.x*xv[0] + a0.y*xv[1] + a0.z*xv[2] + a0.w*xv[3]
                + a1.x*xv[4] + a1.y*xv[5] + a1.z*xv[6] + a1.w*xv[7]
                + a2.x*xv[8] + a2.y*xv[9] + a2.z*xv[10] + a2.w*xv[11]
                + a3.x*xv[12] + a3.y*xv[13] + a3.z*xv[14] + a3.w*xv[15]
                + a4.x*xv[16];
        h1[base + j*H1P] = s;
      }
    }
    __syncthreads();   // (3) mix complete

    if (layer < NLAYERS - 1) {
      // ---- combine A: fold into acc0 (reg-resident; no spill)
      #pragma unroll
      for (int q = 0; q < 16; ++q) {
        int row = wm*32 + (q&3) + 8*(q>>2) + 4*g;
        float x0v = (float)b2h((u16)(x0p[q>>1] >> (16*(q&1))));
        acc0[q] = 0.2f*x0v + diag8[row]*acc0[q] + h1[row*H1P + ccol] + biasl[ccol];
      }
      __syncthreads();   // (4) all h1 reads drained before alias overwrite

      // ---- combine B: acc0 -> X plane (f16 single)
      #pragma unroll
      for (int q = 0; q < 16; ++q) {
        int row = wm*32 + (q&3) + 8*(q>>2) + 4*g;
        xh[row*XP + ccol] = h2b((_Float16)acc0[q]);
      }
      __syncthreads();   // (5) X ready for next layer
    } else {
      // final layer: own-slot RMW into h1, keep f32 for LN
      #pragma unroll
      for (int q = 0; q < 16; ++q) {
        int row = wm*32 + (q&3) + 8*(q>>2) + 4*g;
        float x0v = (float)b2h((u16)(x0p[q>>1] >> (16*(q&1))));
        h1[row*H1P + ccol] = 0.2f*x0v + diag8[row]*acc0[q] + h1[row*H1P + ccol] + biasl[ccol];
      }
      __syncthreads();   // (4) ready for LN
    }
  }

  // ---- LayerNorm + store (reads f32 h1), 16 waves
  float ga = gamma[lane], g2 = gamma[64+lane];
  float ba = beta[lane],  b2f = beta[64+lane];
  #pragma unroll 1
  for (int i = 0; i < 8; ++i) {
    int r = wid + 16*i;            // wave-uniform, 0..127
    if (r >= ROWS) continue;
    int grow = grow0 + r;
    if (grow >= totRows) continue;
    float xa = h1[r*H1P + lane];
    float xc = h1[r*H1P + 64 + lane];
    float mu = wred(xa + xc) * (1.f/128.f);
    float da = xa - mu, dc = xc - mu;
    float vs = wred(da*da + dc*dc) * (1.f/128.f);
    float rs = rsqrtf(vs + 1e-10f);
    size_t ob = (size_t)grow*CC;
    out[ob + lane]      = da*rs*ga + ba;
    out[ob + 64 + lane] = dc*rs*g2 + b2f;
  }
}

extern "C" void kernel_launch(void* const* d_in, const int* in_sizes, int n_in,
                              void* d_out, int out_size, void* d_ws, size_t ws_size,
                              hipStream_t stream) {
  const float* x   = (const float*)d_in[0];
  const float* x0  = (const float*)d_in[1];
  const float* adj = (const float*)d_in[2];
  const float* W0  = (const float*)d_in[3];
  const float* W1  = (const float*)d_in[4];
  const float* bv  = (const float*)d_in[5];
  const float* ga  = (const float*)d_in[6];
  const float* be  = (const float*)d_in[7];
  u16*   wsH  = (u16*)d_ws;                     // [2][128][128] f16 = 65536 B
  float* adjc = (float*)((char*)d_ws + 65536);  // [17][20] f32 = 1360 B
  int totRows = in_sizes[0] / CC;
  int nBatch  = totRows / JJ;
  int grid    = (nBatch + BB - 1) / BB;
  wprep<<<dim3(2), dim3(256), 0, stream>>>(W0, W1, adj, wsH, adjc);
  hipFuncSetAttribute((const void*)gconv_fused,
                      hipFuncAttributeMaxDynamicSharedMemorySize, LDS_BYTES);
  gconv_fused<<<dim3(grid), dim3(NT), LDS_BYTES, stream>>>(
      x, x0, adj, wsH, adjc, bv, ga, be, (float*)d_out, totRows);
}

// Round 18
// 418.331 us; speedup vs baseline: 1.9333x; 1.1796x over previous
//
#include <hip/hip_runtime.h>
#include <stdint.h>

typedef unsigned short u16;
typedef unsigned int   u32;
typedef _Float16 f16x4 __attribute__((ext_vector_type(4)));
typedef _Float16 f16x8 __attribute__((ext_vector_type(8)));
typedef __attribute__((ext_vector_type(16))) float f16v;

#define JJ 17
#define CC 128
#define BB 7
#define ROWS (BB*JJ)     // 119
#define PP 128
#define XP 132           // X pitch (u16): 264B rows, b64-pair frags, low conflict
#define HT 136           // h1t pitch (u16): 272B cols -> b128 frags 16B-aligned
#define NLAYERS 5
#define NT 1024

#define XH_OFF   0                        // xh  [128][132] u16 = 33792
#define HT_OFF   (PP*XP*2)                // h1t [128][136] u16 = 34816 -> ends 68608
#define W_OFF    (HT_OFF + PP*HT*2)       // wlds[2][128][132] u16 = 67584 -> ends 136192
#define LDS_BYTES (W_OFF + 2*PP*XP*2)     // 136192 -> 1 block/CU, 16 waves (4/SIMD)

#define MFMA __builtin_amdgcn_mfma_f32_32x32x16_f16

__device__ __forceinline__ u16 h2b(_Float16 h) {
  union { _Float16 h; u16 b; } c; c.h = h; return c.b;
}
__device__ __forceinline__ _Float16 b2h(u16 b) {
  union { u16 b; _Float16 h; } c; c.b = b; return c.h;
}
__device__ __forceinline__ f16x8 cmbh(f16x4 a, f16x4 b) {
  f16x8 r;
  r[0]=a[0]; r[1]=a[1]; r[2]=a[2]; r[3]=a[3];
  r[4]=b[0]; r[5]=b[1]; r[6]=b[2]; r[7]=b[3];
  return r;
}
__device__ __forceinline__ float wred(float v) {
  #pragma unroll
  for (int m = 32; m >= 1; m >>= 1) v += __shfl_xor(v, m, 64);
  return v;
}
__device__ __forceinline__ f16x8 u4f8(uint4 v) {
  union { uint4 u; f16x8 f; } c; c.u = v; return c.f;
}

// ---- setup: W->f16 frag layout [w][col][k]; Amix MFMA A-frags [wm][i][g][nl][8]
__global__ void __launch_bounds__(256)
wprep(const float* __restrict__ W0, const float* __restrict__ W1,
      const float* __restrict__ adj, u16* __restrict__ wsH,
      u16* __restrict__ amixf)
{
  __shared__ float wt[64*130];
  const int w01 = blockIdx.x;
  const float* Wp = w01 ? W1 : W0;
  const int tid = threadIdx.x;
  if (w01 == 0) {
    // amixf[t]: t = ((wm*4+i)*2+g)*256 + nl*8 + e ; ks = kslo[wm]+i
    for (int t = tid; t < 8192; t += 256) {
      int e  = t & 7, nl = (t >> 3) & 31, g = (t >> 8) & 1;
      int i  = (t >> 9) & 3, wm = t >> 11;
      const int kslo = (wm==0)?0:(wm==1)?1:(wm==2)?3:4;
      int row = wm*32 + nl;
      int k   = (kslo + i)*16 + 8*g + e;
      float v = 0.f;
      if (row < ROWS && k < ROWS && (row/JJ) == (k/JJ) && (row%JJ) != (k%JJ))
        v = 0.8f * adj[(row%JJ)*JJ + (k%JJ)];
      amixf[t] = h2b((_Float16)v);
    }
  }
  for (int kh = 0; kh < 2; ++kh) {
    if (kh) __syncthreads();
    #pragma unroll
    for (int i = 0; i < 32; ++i) {
      int idx = tid + i*256;           // [64 kk][128 col] coalesced read
      int kk = idx >> 7, col = idx & 127;
      wt[kk*130 + col] = Wp[(kh*64 + kk)*128 + col];
    }
    __syncthreads();
    #pragma unroll
    for (int i = 0; i < 32; ++i) {
      int idx = tid + i*256;           // [128 col][64 kk] coalesced write
      int col = idx >> 6, kk = idx & 63;
      wsH[(size_t)(w01*128 + col)*128 + kh*64 + kk] = h2b((_Float16)wt[kk*130 + col]);
    }
  }
}

__global__ void __launch_bounds__(NT, 4)
gconv_fused(const float* __restrict__ x, const float* __restrict__ x0,
            const float* __restrict__ adj, const u16* __restrict__ wsH,
            const u16* __restrict__ amixf, const float* __restrict__ bvec,
            const float* __restrict__ gamma, const float* __restrict__ beta,
            float* __restrict__ out, int totRows)
{
  extern __shared__ char smem[];
  u16* xh   = (u16*)(smem + XH_OFF);   // [128][132] x (f16)
  u16* h1t  = (u16*)(smem + HT_OFF);   // [128 col][136] f16 H1 transposed
  u16* wlds = (u16*)(smem + W_OFF);    // [2][128][132] f16 W frag layout

  const int tid  = threadIdx.x;
  const int lane = tid & 63;
  const int wid  = tid >> 6;        // 0..15
  const int wm   = wid >> 2;        // 0..3  M-tile (32 rows)
  const int wn   = wid & 3;         // 0..3  N-tile (32 cols)
  const int g    = lane >> 5;
  const int nl   = lane & 31;
  const int ccol = wn*32 + nl;
  const int grow0 = blockIdx.x * ROWS;
  const int kslo = (wm==0)?0:(wm==1)?1:(wm==2)?3:4;

  // ---- Amix A-frags (constant): 4x uint4 = 16 VGPRs
  f16x8 amx[4];
  #pragma unroll
  for (int i = 0; i < 4; ++i)
    amx[i] = u4f8(*(const uint4*)&amixf[(((wm*4+i)*2)+g)*256 + nl*8]);

  // ---- W (f16) -> LDS: 32 contiguous u16/thread, 8B writes
  {
    int el = tid * 32;                 // 0..32767
    int w01 = el >> 14, rem = el & 16383;
    int col = rem >> 7, k0 = rem & 127;
    const u16* src = wsH + el;
    u16* dst = &wlds[(w01*128 + col)*XP + k0];
    #pragma unroll
    for (int c = 0; c < 8; ++c)
      *(uint2*)(dst + c*4) = *(const uint2*)(src + c*4);
  }

  // ---- x0, diag -> packed f16 regs (accumulator layout), read once
  u32 x0p[8], dpk[8];
  #pragma unroll
  for (int qp = 0; qp < 8; ++qp) {
    u32 pk = 0, dk = 0;
    #pragma unroll
    for (int h = 0; h < 2; ++h) {
      int q = qp*2 + h;
      int row = wm*32 + (q&3) + 8*(q>>2) + 4*g;
      int grow = grow0 + row;
      u16 xb = 0, db = 0;
      if (row < ROWS && grow < totRows) {
        xb = h2b((_Float16)x0[(size_t)grow*CC + ccol]);
        int j = row % JJ;
        db = h2b((_Float16)(0.8f * adj[j*JJ + j]));
      }
      pk |= ((u32)xb) << (16*h);
      dk |= ((u32)db) << (16*h);
    }
    x0p[qp] = pk; dpk[qp] = dk;
  }
  const float bias_c = bvec[ccol];

  // ---- x -> xh f16 plane (float4 in); pad rows zero
  #pragma unroll
  for (int i = 0; i < 4; ++i) {
    int el4 = tid + i*NT;              // 4096 float4 = 128 rows x 128
    int r = el4 >> 5, c4 = (el4 & 31) << 2;
    float4 v = make_float4(0.f, 0.f, 0.f, 0.f);
    if (r < ROWS && (grow0 + r) < totRows)
      v = *(const float4*)&x[(size_t)(grow0 + r)*CC + c4];
    u16 s0 = h2b((_Float16)v.x), s1 = h2b((_Float16)v.y);
    u16 s2 = h2b((_Float16)v.z), s3 = h2b((_Float16)v.w);
    *(uint2*)&xh[r*XP + c4] = make_uint2((u32)s0 | ((u32)s1<<16), (u32)s2 | ((u32)s3<<16));
  }
  __syncthreads();

  const int arow = (wm*32 + nl)*XP;            // A base (+= ks*16 + 8g)
  const int bb0  = ccol*XP;                    // W0 frag base
  const int bb1  = bb0 + 128*XP;               // W1
  const int htb  = ccol*HT + 8*g;              // h1t frag base (+= ks*16)

  // ================= layer loop (2 barriers; no global traffic) =================
  #pragma unroll 1
  for (int layer = 0; layer < NLAYERS; ++layer) {
    f16v acc0, acc1;
    #pragma unroll
    for (int i = 0; i < 16; ++i) { acc0[i] = 0.f; acc1[i] = 0.f; }

    // ---- GEMM: per ks: 3 b64-pair reads + 2 MFMA
    #pragma unroll
    for (int ks = 0; ks < 8; ++ks) {
      const int o = ks*16 + 8*g;
      f16x8 ah = cmbh(*(const f16x4*)&xh[arow + o],   *(const f16x4*)&xh[arow + o + 4]);
      f16x8 b0 = cmbh(*(const f16x4*)&wlds[bb0 + o],  *(const f16x4*)&wlds[bb0 + o + 4]);
      f16x8 b1 = cmbh(*(const f16x4*)&wlds[bb1 + o],  *(const f16x4*)&wlds[bb1 + o + 4]);
      acc0 = MFMA(ah, b0, acc0, 0, 0, 0);
      acc1 = MFMA(ah, b1, acc1, 0, 0, 0);
      __builtin_amdgcn_sched_barrier(0);   // cap fragment liveness per K-step
    }

    // ---- epilogue: acc1 (X@W1) -> h1t TRANSPOSED, f16 pairs (8 u32 writes)
    #pragma unroll
    for (int qp = 0; qp < 8; ++qp) {
      int q = qp*2;
      int row = wm*32 + (q&3) + 8*(q>>2) + 4*g;      // even; row+1 is q+1
      u32 pk = (u32)h2b((_Float16)acc1[q]) | ((u32)h2b((_Float16)acc1[q+1]) << 16);
      *(u32*)&h1t[ccol*HT + row] = pk;
    }
    __syncthreads();   // (1) h1t complete; all xh GEMM reads done

    // ---- mix GEMM: acc1 (reused) = Amix * H1, 4 MFMAs (block-diag K window)
    #pragma unroll
    for (int i = 0; i < 16; ++i) acc1[i] = 0.f;
    #pragma unroll
    for (int i = 0; i < 4; ++i) {
      f16x8 hb = u4f8(*(const uint4*)&h1t[htb + (kslo + i)*16]);
      acc1 = MFMA(amx[i], hb, acc1, 0, 0, 0);
    }

    // ---- combine: pure-register -> new X (f16)
    #pragma unroll
    for (int q = 0; q < 16; ++q) {
      int row = wm*32 + (q&3) + 8*(q>>2) + 4*g;
      float x0v = (float)b2h((u16)(x0p[q>>1] >> (16*(q&1))));
      float dg  = (float)b2h((u16)(dpk[q>>1] >> (16*(q&1))));
      float v = 0.2f*x0v + dg*acc0[q] + acc1[q] + bias_c;
      xh[row*XP + ccol] = h2b((_Float16)v);
    }
    __syncthreads();   // (2) X ready; h1t reads drained
  }

  // ---- LayerNorm + store (reads f16 X), 16 waves
  float ga = gamma[lane], g2 = gamma[64+lane];
  float ba = beta[lane],  b2f = beta[64+lane];
  #pragma unroll 1
  for (int i = 0; i < 8; ++i) {
    int r = wid + 16*i;            // wave-uniform, 0..127
    if (r >= ROWS) continue;
    int grow = grow0 + r;
    if (grow >= totRows) continue;
    float xa = (float)b2h(xh[r*XP + lane]);
    float xc = (float)b2h(xh[r*XP + 64 + lane]);
    float mu = wred(xa + xc) * (1.f/128.f);
    float da = xa - mu, dc = xc - mu;
    float vs = wred(da*da + dc*dc) * (1.f/128.f);
    float rs = rsqrtf(vs + 1e-10f);
    size_t ob = (size_t)grow*CC;
    out[ob + lane]      = da*rs*ga + ba;
    out[ob + 64 + lane] = dc*rs*g2 + b2f;
  }
}

extern "C" void kernel_launch(void* const* d_in, const int* in_sizes, int n_in,
                              void* d_out, int out_size, void* d_ws, size_t ws_size,
                              hipStream_t stream) {
  const float* x   = (const float*)d_in[0];
  const float* x0  = (const float*)d_in[1];
  const float* adj = (const float*)d_in[2];
  const float* W0  = (const float*)d_in[3];
  const float* W1  = (const float*)d_in[4];
  const float* bv  = (const float*)d_in[5];
  const float* ga  = (const float*)d_in[6];
  const float* be  = (const float*)d_in[7];
  u16* wsH   = (u16*)d_ws;                      // [2][128][128] f16 = 65536 B
  u16* amixf = (u16*)((char*)d_ws + 65536);     // [4][4][2][32][8] f16 = 16384 B
  int totRows = in_sizes[0] / CC;
  int nBatch  = totRows / JJ;
  int grid    = (nBatch + BB - 1) / BB;
  wprep<<<dim3(2), dim3(256), 0, stream>>>(W0, W1, adj, wsH, amixf);
  hipFuncSetAttribute((const void*)gconv_fused,
                      hipFuncAttributeMaxDynamicSharedMemorySize, LDS_BYTES);
  gconv_fused<<<dim3(grid), dim3(NT), LDS_BYTES, stream>>>(
      x, x0, adj, wsH, amixf, bv, ga, be, (float*)d_out, totRows);
}